// Round 7
// baseline (999.568 us; speedup 1.0000x reference)
//
#include <hip/hip_runtime.h>
#include <hip/hip_bf16.h>
#include <cstdint>
#include <cstddef>

#define N_NODES 100000
#define NFEAT 512
#define NHID 256
#define NCLASS 128
#define K_HOPS 5
#define ALPHA 0.1f

typedef __attribute__((ext_vector_type(8))) short short8v;   // 8 bf16 (4 VGPRs)
typedef __attribute__((ext_vector_type(4))) float f32x4;     // MFMA accumulator

__device__ __forceinline__ unsigned short f2bf(float f) {
    unsigned u = __builtin_bit_cast(unsigned, f);
    u += 0x7FFFu + ((u >> 16) & 1u);      // round-to-nearest-even
    return (unsigned short)(u >> 16);
}
__device__ __forceinline__ float bflo(unsigned u) {
    return __builtin_bit_cast(float, u << 16);
}
__device__ __forceinline__ float bfhi(unsigned u) {
    return __builtin_bit_cast(float, u & 0xFFFF0000u);
}
__device__ __forceinline__ unsigned cvtpk2(float a, float b) {
    unsigned r;
    asm("v_cvt_pk_bf16_f32 %0, %1, %2" : "=v"(r) : "v"(a), "v"(b));
    return r;   // low16 = bf16(a), high16 = bf16(b)
}
__device__ __forceinline__ void gload_lds16(const void* g, void* l) {
    __builtin_amdgcn_global_load_lds((const __attribute__((address_space(1))) void*)g,
                                     (__attribute__((address_space(3))) void*)l, 16, 0, 0);
}

// ---------------------------------------------------------------------------
// CSR build: histogram -> hierarchical scan -> scatter (packed int2 metadata)
// ---------------------------------------------------------------------------

__global__ void count_kernel(const int* __restrict__ dst, int* __restrict__ counts, int E) {
    int i = blockIdx.x * blockDim.x + threadIdx.x;
    if (i < E) atomicAdd(&counts[dst[i]], 1);
}

__global__ __launch_bounds__(256) void scan_p1(const int* __restrict__ counts,
                                               int* __restrict__ partial, int n) {
    __shared__ int ws[4];
    int b = blockIdx.x, t = threadIdx.x;
    int base = b * 1024 + t * 4;
    int s = 0;
#pragma unroll
    for (int j = 0; j < 4; ++j) {
        int idx = base + j;
        if (idx < n) s += counts[idx];
    }
#pragma unroll
    for (int off = 32; off; off >>= 1) s += __shfl_xor(s, off, 64);
    if ((t & 63) == 0) ws[t >> 6] = s;
    __syncthreads();
    if (t == 0) partial[b] = ws[0] + ws[1] + ws[2] + ws[3];
}

__global__ __launch_bounds__(128) void scan_p2(int* __restrict__ partial, int nb) {
    __shared__ int s[128];
    int t = threadIdx.x;
    int v = (t < nb) ? partial[t] : 0;
    s[t] = v;
    __syncthreads();
    for (int off = 1; off < 128; off <<= 1) {
        int u = (t >= off) ? s[t - off] : 0;
        __syncthreads();
        s[t] += u;
        __syncthreads();
    }
    if (t < nb) partial[t] = (t == 0) ? 0 : s[t - 1];
}

__global__ __launch_bounds__(256) void scan_p3(const int* __restrict__ counts,
                                               const int* __restrict__ partial,
                                               int* __restrict__ row_ptr,
                                               int* __restrict__ fill, int n) {
    __shared__ int ts[256];
    int b = blockIdx.x, t = threadIdx.x;
    int base = b * 1024 + t * 4;
    int c[4];
#pragma unroll
    for (int j = 0; j < 4; ++j) {
        int idx = base + j;
        c[j] = (idx < n) ? counts[idx] : 0;
    }
    int s = c[0] + c[1] + c[2] + c[3];
    ts[t] = s;
    __syncthreads();
    for (int off = 1; off < 256; off <<= 1) {
        int v = (t >= off) ? ts[t - off] : 0;
        __syncthreads();
        ts[t] += v;
        __syncthreads();
    }
    int pre = partial[b] + ((t == 0) ? 0 : ts[t - 1]);
#pragma unroll
    for (int j = 0; j < 4; ++j) {
        int idx = base + j;
        if (idx < n) {
            row_ptr[idx] = pre;
            fill[idx] = pre;
            if (idx == n - 1) row_ptr[n] = pre + c[j];
            pre += c[j];
        }
    }
}

__global__ void scatter_kernel(const int* __restrict__ src, const int* __restrict__ dst,
                               const float* __restrict__ w, int* __restrict__ fill,
                               int2* __restrict__ epk, int E) {
    int i = blockIdx.x * blockDim.x + threadIdx.x;
    if (i < E) {
        int d = dst[i];
        int pos = atomicAdd(&fill[d], 1);
        int2 m; m.x = src[i]; m.y = __builtin_bit_cast(int, w[i]);
        epk[pos] = m;
    }
}

// ---------------------------------------------------------------------------
// Weight transpose + bf16 convert: Wt[n][k] = bf16(W[k][n])
// ---------------------------------------------------------------------------
__global__ void wtrans_kernel(const float* __restrict__ W, unsigned short* __restrict__ Wt,
                              int K, int N) {
    int idx = blockIdx.x * blockDim.x + threadIdx.x;
    if (idx >= N * K) return;
    int n = idx / K, k = idx - n * K;
    Wt[idx] = f2bf(W[(size_t)k * N + n]);
}

// ---------------------------------------------------------------------------
// GEMM layer 1 (unchanged this round; known ~140us, TA-request-rate-bound)
// ---------------------------------------------------------------------------
__global__ __launch_bounds__(512) void gemm1_pipe(const float* __restrict__ X,
                                                  const unsigned short* __restrict__ W1t,
                                                  const float* __restrict__ b1,
                                                  unsigned short* __restrict__ Hb, int M) {
    __shared__ char smem[131072];          // 4x16KB A (f32) + 4x16KB B (bf16)
    char* const Ab0 = smem;
    char* const Bb0 = smem + 65536;

    const int tid = threadIdx.x;
    const int lane = tid & 63;
    const int wv = tid >> 6;               // 0..7
    const int wr = wv >> 2, wc = wv & 3;   // 2 x 4 wave grid
    const int brow = blockIdx.x * 128;

    const char* asrc[2];
    int adst[2];
#pragma unroll
    for (int c = 0; c < 2; ++c) {
        int ar = brow + wv * 16 + (lane & 15); if (ar > M - 1) ar = M - 1;
        int k = (lane >> 4) * 8 + c * 4;
        asrc[c] = (const char*)&X[(size_t)ar * NFEAT + k];
        adst[c] = (wv + c * 8) * 1024;
    }
    const char* bsrc[2];
    int bdst[2];
#pragma unroll
    for (int c = 0; c < 2; ++c) {
        int ci = wv + c * 8;
        int col = ci * 16 + (lane & 15);
        bsrc[c] = (const char*)&W1t[(size_t)col * NFEAT + (lane >> 4) * 8];
        bdst[c] = ci * 1024;
    }

    f32x4 acc[4][4];
#pragma unroll
    for (int m = 0; m < 4; ++m)
#pragma unroll
        for (int n = 0; n < 4; ++n) acc[m][n] = f32x4{0.f, 0.f, 0.f, 0.f};

    auto stage = [&](int buf, int step) {
#pragma unroll
        for (int c = 0; c < 2; ++c)
            gload_lds16(asrc[c] + (size_t)step * 128, Ab0 + buf * 16384 + adst[c]);
#pragma unroll
        for (int c = 0; c < 2; ++c)
            gload_lds16(bsrc[c] + (size_t)step * 64, Bb0 + buf * 16384 + bdst[c]);
    };

    constexpr int NSTEP = NFEAT / 32;      // 16
    stage(0, 0);
    stage(1, 1);

    for (int s = 0; s < NSTEP; ++s) {
        if (s + 2 < NSTEP) {
            stage((s + 2) & 3, s + 2);
            asm volatile("s_waitcnt vmcnt(8)" ::: "memory");
        } else if (s + 1 < NSTEP) {
            asm volatile("s_waitcnt vmcnt(4)" ::: "memory");
        } else {
            asm volatile("s_waitcnt vmcnt(0)" ::: "memory");
        }
        __builtin_amdgcn_s_barrier();
        asm volatile("" ::: "memory");

        const char* Abuf = Ab0 + (s & 3) * 16384;
        const char* Bbuf = Bb0 + (s & 3) * 16384;
        short8v a[4], b[4];
#pragma unroll
        for (int m = 0; m < 4; ++m) {
            int g = ((wr * 4 + m) * 64 + lane) * 16;
            f32x4 lo = *(const f32x4*)(Abuf + g);
            f32x4 hi = *(const f32x4*)(Abuf + 8192 + g);
            uint4 u;
            u.x = cvtpk2(lo[0], lo[1]); u.y = cvtpk2(lo[2], lo[3]);
            u.z = cvtpk2(hi[0], hi[1]); u.w = cvtpk2(hi[2], hi[3]);
            a[m] = __builtin_bit_cast(short8v, u);
        }
#pragma unroll
        for (int n = 0; n < 4; ++n)
            b[n] = *(const short8v*)(Bbuf + ((wc * 4 + n) * 64 + lane) * 16);
#pragma unroll
        for (int m = 0; m < 4; ++m)
#pragma unroll
            for (int n = 0; n < 4; ++n)
                acc[m][n] = __builtin_amdgcn_mfma_f32_16x16x32_bf16(a[m], b[n], acc[m][n], 0, 0, 0);

        __builtin_amdgcn_s_barrier();
        asm volatile("" ::: "memory");
    }

#pragma unroll
    for (int n = 0; n < 4; ++n) {
        int colg = wc * 64 + n * 16 + (lane & 15);
        float bv = b1[colg];
#pragma unroll
        for (int m = 0; m < 4; ++m) {
#pragma unroll
            for (int r = 0; r < 4; ++r) {
                int rowg = brow + wr * 64 + m * 16 + (lane >> 4) * 4 + r;
                if (rowg < M) {
                    float v = fmaxf(acc[m][n][r] + bv, 0.f);
                    Hb[(size_t)rowg * NHID + colg] = f2bf(v);
                }
            }
        }
    }
}

// ---------------------------------------------------------------------------
// GEMM layer 2 (unchanged)
// ---------------------------------------------------------------------------
__global__ __launch_bounds__(256) void gemm2_pipe(const unsigned short* __restrict__ Hb,
                                                  const unsigned short* __restrict__ W2t,
                                                  const float* __restrict__ b2,
                                                  unsigned short* __restrict__ C0, int M) {
    __shared__ char smem[65536];           // 4x8KB A + 4x8KB B
    char* const Ab0 = smem;
    char* const Bb0 = smem + 32768;

    const int tid = threadIdx.x;
    const int lane = tid & 63;
    const int wv = tid >> 6;               // 0..3
    const int wr = wv >> 1, wc = wv & 1;
    const int brow = blockIdx.x * 128;

    const char* asrc[2];
    const char* bsrc[2];
    int adst[2], bdst[2];
#pragma unroll
    for (int c = 0; c < 2; ++c) {
        int ci = wv + c * 4;               // 0..7
        int ar = brow + ci * 16 + (lane & 15); if (ar > M - 1) ar = M - 1;
        asrc[c] = (const char*)&Hb[(size_t)ar * NHID + (lane >> 4) * 8];
        adst[c] = ci * 1024;
        int col = ci * 16 + (lane & 15);
        bsrc[c] = (const char*)&W2t[(size_t)col * NHID + (lane >> 4) * 8];
        bdst[c] = ci * 1024;
    }

    f32x4 acc[4][4];
#pragma unroll
    for (int m = 0; m < 4; ++m)
#pragma unroll
        for (int n = 0; n < 4; ++n) acc[m][n] = f32x4{0.f, 0.f, 0.f, 0.f};

    auto stage = [&](int buf, int step) {
#pragma unroll
        for (int c = 0; c < 2; ++c)
            gload_lds16(asrc[c] + (size_t)step * 64, Ab0 + buf * 8192 + adst[c]);
#pragma unroll
        for (int c = 0; c < 2; ++c)
            gload_lds16(bsrc[c] + (size_t)step * 64, Bb0 + buf * 8192 + bdst[c]);
    };

    constexpr int NSTEP = NHID / 32;       // 8
    stage(0, 0);
    stage(1, 1);

    for (int s = 0; s < NSTEP; ++s) {
        if (s + 2 < NSTEP) {
            stage((s + 2) & 3, s + 2);
            asm volatile("s_waitcnt vmcnt(8)" ::: "memory");
        } else if (s + 1 < NSTEP) {
            asm volatile("s_waitcnt vmcnt(4)" ::: "memory");
        } else {
            asm volatile("s_waitcnt vmcnt(0)" ::: "memory");
        }
        __builtin_amdgcn_s_barrier();
        asm volatile("" ::: "memory");

        const char* Abuf = Ab0 + (s & 3) * 8192;
        const char* Bbuf = Bb0 + (s & 3) * 8192;
        short8v a[4], b[4];
#pragma unroll
        for (int m = 0; m < 4; ++m)
            a[m] = *(const short8v*)(Abuf + ((wr * 4 + m) * 64 + lane) * 16);
#pragma unroll
        for (int n = 0; n < 4; ++n)
            b[n] = *(const short8v*)(Bbuf + ((wc * 4 + n) * 64 + lane) * 16);
#pragma unroll
        for (int m = 0; m < 4; ++m)
#pragma unroll
            for (int n = 0; n < 4; ++n)
                acc[m][n] = __builtin_amdgcn_mfma_f32_16x16x32_bf16(a[m], b[n], acc[m][n], 0, 0, 0);

        __builtin_amdgcn_s_barrier();
        asm volatile("" ::: "memory");
    }

#pragma unroll
    for (int n = 0; n < 4; ++n) {
        int colg = wc * 64 + n * 16 + (lane & 15);
        float bv = b2[colg];
#pragma unroll
        for (int m = 0; m < 4; ++m) {
#pragma unroll
            for (int r = 0; r < 4; ++r) {
                int rowg = brow + wr * 64 + m * 16 + (lane >> 4) * 4 + r;
                if (rowg < M)
                    C0[(size_t)rowg * NCLASS + colg] = f2bf(acc[m][n][r] + bv);
            }
        }
    }
}

// ---------------------------------------------------------------------------
// Grouped propagation hop: channels split into 4 groups of 32 so the active
// gather slice (100k x 32ch bf16 = 6.4MB) approaches per-XCD L2 capacity.
// grid = (ceil(N/4), 4 groups); wave = 1 node; 4 edges in parallel
// (16 lanes x 4B = one 64B line per edge). Edge meta broadcast via __shfl
// with per-lane slot index; zero-padded meta lanes make tail weights 0.0.
// Cross-slot reduce via shfl_xor(16,32). FINAL writes f32 (softmax separate).
// ---------------------------------------------------------------------------
template<int FINAL>
__global__ __launch_bounds__(256) void hop_grp(const unsigned short* __restrict__ carry,
                                               const unsigned short* __restrict__ c0,
                                               const int* __restrict__ rp,
                                               const int2* __restrict__ epk,
                                               unsigned short* __restrict__ outb,
                                               float* __restrict__ outf, int nnodes) {
    int node = blockIdx.x * 4 + (threadIdx.x >> 6);
    if (node >= nnodes) return;
    const int g = blockIdx.y;              // channel group 0..3
    const int lane = threadIdx.x & 63;
    const int sub = lane >> 4;             // edge slot 0..3
    const int c = lane & 15;               // channel-pair 0..15 within group
    const int gbase = g * 16 + c;          // u32 index within a 64-u32 row
    const unsigned* cu = (const unsigned*)carry;

    int e0 = rp[node], e1 = rp[node + 1];
    float ax = 0.f, ay = 0.f;

    for (int eb = e0; eb < e1; eb += 64) {
        int nb = e1 - eb; if (nb > 64) nb = 64;
        int cs = 0, wv = 0;
        if (lane < nb) {
            int2 m = epk[eb + lane];
            cs = m.x; wv = m.y;            // lanes >= nb keep {0, 0.0f}
        }
        for (int j = 0; j < nb; j += 16) { // 4 edges/slot-iter x 4 slots
            int i0 = j + sub, i1 = i0 + 4, i2 = i0 + 8, i3 = i0 + 12;   // < 64 always
            int s0 = __shfl(cs, i0, 64); float w0 = __builtin_bit_cast(float, __shfl(wv, i0, 64));
            int s1 = __shfl(cs, i1, 64); float w1 = __builtin_bit_cast(float, __shfl(wv, i1, 64));
            int s2 = __shfl(cs, i2, 64); float w2 = __builtin_bit_cast(float, __shfl(wv, i2, 64));
            int s3 = __shfl(cs, i3, 64); float w3 = __builtin_bit_cast(float, __shfl(wv, i3, 64));
            unsigned u0 = cu[(size_t)s0 * 64 + gbase];
            unsigned u1 = cu[(size_t)s1 * 64 + gbase];
            unsigned u2 = cu[(size_t)s2 * 64 + gbase];
            unsigned u3 = cu[(size_t)s3 * 64 + gbase];
            ax = fmaf(w0, bflo(u0), ax); ay = fmaf(w0, bfhi(u0), ay);
            ax = fmaf(w1, bflo(u1), ax); ay = fmaf(w1, bfhi(u1), ay);
            ax = fmaf(w2, bflo(u2), ax); ay = fmaf(w2, bfhi(u2), ay);
            ax = fmaf(w3, bflo(u3), ax); ay = fmaf(w3, bfhi(u3), ay);
        }
    }

    // reduce across the 4 edge slots (same channel-pair c)
    ax += __shfl_xor(ax, 16, 64); ax += __shfl_xor(ax, 32, 64);
    ay += __shfl_xor(ay, 16, 64); ay += __shfl_xor(ay, 32, 64);

    if (lane < 16) {
        unsigned u = ((const unsigned*)c0)[(size_t)node * 64 + gbase];
        float vx = (1.f - ALPHA) * ax + ALPHA * bflo(u);
        float vy = (1.f - ALPHA) * ay + ALPHA * bfhi(u);
        if (FINAL) {
            float2 o; o.x = vx; o.y = vy;
            ((float2*)outf)[(size_t)node * 64 + gbase] = o;
        } else {
            ((unsigned*)outb)[(size_t)node * 64 + gbase] =
                (unsigned)f2bf(vx) | ((unsigned)f2bf(vy) << 16);
        }
    }
}

// ---------------------------------------------------------------------------
// In-place log_softmax over f32 rows of 128: one wave per node
// ---------------------------------------------------------------------------
__global__ __launch_bounds__(256) void logsoftmax_kernel(float* __restrict__ buf, int nnodes) {
    int node = blockIdx.x * 4 + (threadIdx.x >> 6);
    if (node >= nnodes) return;
    int lane = threadIdx.x & 63;
    float2* p = (float2*)(buf + ((size_t)node << 7)) + lane;
    float2 v = *p;
    float m = fmaxf(v.x, v.y);
#pragma unroll
    for (int off = 32; off; off >>= 1) m = fmaxf(m, __shfl_xor(m, off, 64));
    float s = __expf(v.x - m) + __expf(v.y - m);
#pragma unroll
    for (int off = 32; off; off >>= 1) s += __shfl_xor(s, off, 64);
    float l = m + __logf(s);
    float2 o; o.x = v.x - l; o.y = v.y - l;
    *p = o;
}

// ---------------------------------------------------------------------------

extern "C" void kernel_launch(void* const* d_in, const int* in_sizes, int n_in,
                              void* d_out, int out_size, void* d_ws, size_t ws_size,
                              hipStream_t stream) {
    const float* x   = (const float*)d_in[0];
    const int*   ei  = (const int*)d_in[1];
    const float* ew  = (const float*)d_in[2];
    const float* W1  = (const float*)d_in[3];
    const float* b1  = (const float*)d_in[4];
    const float* W2  = (const float*)d_in[5];
    const float* b2  = (const float*)d_in[6];
    float* outp = (float*)d_out;

    const int E = in_sizes[1] / 2;
    const int Nn = N_NODES;
    const int* srcv = ei;
    const int* dstv = ei + E;
    const size_t NC = (size_t)Nn * NCLASS;   // 12.8M elements

    // workspace layout (16B-aligned buffers)
    unsigned short* c0  = (unsigned short*)d_ws;    // bf16 x0 copy     [NC]
    unsigned short* A16 = c0 + NC;                  // ping             [NC]
    unsigned short* B16 = A16 + NC;                 // pong             [NC]
    unsigned short* hb  = A16;                      // H bf16 overlay (dead before hops)
    unsigned short* w1t = B16 + NC;                 // 256x512
    unsigned short* w2t = w1t + NHID * NFEAT;       // 128x256
    int* row_ptr = (int*)(w2t + NCLASS * NHID);     // Nn+1
    int* fill    = row_ptr + (Nn + 1);              // Nn (counts)
    int* partial = fill + Nn;                       // 128
    int2* epk    = (int2*)(partial + 128);          // E packed {src, w}

    const int NB = (Nn + 1023) / 1024;              // 98 scan blocks

    // ---- CSR build ----
    hipMemsetAsync(fill, 0, (size_t)Nn * sizeof(int), stream);
    count_kernel<<<(E + 255) / 256, 256, 0, stream>>>(dstv, fill, E);
    scan_p1<<<NB, 256, 0, stream>>>(fill, partial, Nn);
    scan_p2<<<1, 128, 0, stream>>>(partial, NB);
    scan_p3<<<NB, 256, 0, stream>>>(fill, partial, row_ptr, fill, Nn);
    scatter_kernel<<<(E + 255) / 256, 256, 0, stream>>>(srcv, dstv, ew, fill, epk, E);

    // ---- weight prep ----
    wtrans_kernel<<<(NHID * NFEAT + 255) / 256, 256, 0, stream>>>(W1, w1t, NFEAT, NHID);
    wtrans_kernel<<<(NCLASS * NHID + 255) / 256, 256, 0, stream>>>(W2, w2t, NHID, NCLASS);

    // ---- MLP (bf16 MFMA, depth-2 counted-vmcnt pipeline) ----
    {
        int gm = (Nn + 127) / 128;                  // 782
        gemm1_pipe<<<gm, 512, 0, stream>>>(x, w1t, b1, hb, Nn);
        gemm2_pipe<<<gm, 256, 0, stream>>>(hb, w2t, b2, c0, Nn);
    }

    // ---- K_HOPS propagation (bf16 carry, channel-grouped), ping-pong ----
    dim3 gh((Nn + 3) / 4, 4);
    const unsigned short* carry = c0;
    unsigned short* dsts[2] = {A16, B16};
    for (int k = 0; k < K_HOPS - 1; ++k) {
        unsigned short* o = dsts[k & 1];
        hop_grp<0><<<gh, 256, 0, stream>>>(carry, c0, row_ptr, epk, o, nullptr, Nn);
        carry = o;
    }
    hop_grp<1><<<gh, 256, 0, stream>>>(carry, c0, row_ptr, epk, nullptr, outp, Nn);

    // ---- log_softmax in-place on d_out ----
    logsoftmax_kernel<<<(Nn + 3) / 4, 256, 0, stream>>>(outp, Nn);
}

// Round 8
// 666.080 us; speedup vs baseline: 1.5007x; 1.5007x over previous
//
#include <hip/hip_runtime.h>
#include <hip/hip_bf16.h>
#include <cstdint>
#include <cstddef>

#define N_NODES 100000
#define NFEAT 512
#define NHID 256
#define NCLASS 128
#define K_HOPS 5
#define ALPHA 0.1f

typedef __attribute__((ext_vector_type(8))) short short8v;   // 8 bf16 (4 VGPRs)
typedef __attribute__((ext_vector_type(4))) float f32x4;     // MFMA accumulator

__device__ __forceinline__ unsigned short f2bf(float f) {
    unsigned u = __builtin_bit_cast(unsigned, f);
    u += 0x7FFFu + ((u >> 16) & 1u);      // round-to-nearest-even
    return (unsigned short)(u >> 16);
}
__device__ __forceinline__ float bflo(unsigned u) {
    return __builtin_bit_cast(float, u << 16);
}
__device__ __forceinline__ float bfhi(unsigned u) {
    return __builtin_bit_cast(float, u & 0xFFFF0000u);
}
__device__ __forceinline__ unsigned cvtpk2(float a, float b) {
    unsigned r;
    asm("v_cvt_pk_bf16_f32 %0, %1, %2" : "=v"(r) : "v"(a), "v"(b));
    return r;   // low16 = bf16(a), high16 = bf16(b)
}
__device__ __forceinline__ void gload_lds16(const void* g, void* l) {
    __builtin_amdgcn_global_load_lds((const __attribute__((address_space(1))) void*)g,
                                     (__attribute__((address_space(3))) void*)l, 16, 0, 0);
}

// ---------------------------------------------------------------------------
// CSR build: histogram -> hierarchical scan -> scatter (packed int2 metadata)
// ---------------------------------------------------------------------------

__global__ void count_kernel(const int* __restrict__ dst, int* __restrict__ counts, int E) {
    int i = blockIdx.x * blockDim.x + threadIdx.x;
    if (i < E) atomicAdd(&counts[dst[i]], 1);
}

__global__ __launch_bounds__(256) void scan_p1(const int* __restrict__ counts,
                                               int* __restrict__ partial, int n) {
    __shared__ int ws[4];
    int b = blockIdx.x, t = threadIdx.x;
    int base = b * 1024 + t * 4;
    int s = 0;
#pragma unroll
    for (int j = 0; j < 4; ++j) {
        int idx = base + j;
        if (idx < n) s += counts[idx];
    }
#pragma unroll
    for (int off = 32; off; off >>= 1) s += __shfl_xor(s, off, 64);
    if ((t & 63) == 0) ws[t >> 6] = s;
    __syncthreads();
    if (t == 0) partial[b] = ws[0] + ws[1] + ws[2] + ws[3];
}

__global__ __launch_bounds__(128) void scan_p2(int* __restrict__ partial, int nb) {
    __shared__ int s[128];
    int t = threadIdx.x;
    int v = (t < nb) ? partial[t] : 0;
    s[t] = v;
    __syncthreads();
    for (int off = 1; off < 128; off <<= 1) {
        int u = (t >= off) ? s[t - off] : 0;
        __syncthreads();
        s[t] += u;
        __syncthreads();
    }
    if (t < nb) partial[t] = (t == 0) ? 0 : s[t - 1];
}

__global__ __launch_bounds__(256) void scan_p3(const int* __restrict__ counts,
                                               const int* __restrict__ partial,
                                               int* __restrict__ row_ptr,
                                               int* __restrict__ fill, int n) {
    __shared__ int ts[256];
    int b = blockIdx.x, t = threadIdx.x;
    int base = b * 1024 + t * 4;
    int c[4];
#pragma unroll
    for (int j = 0; j < 4; ++j) {
        int idx = base + j;
        c[j] = (idx < n) ? counts[idx] : 0;
    }
    int s = c[0] + c[1] + c[2] + c[3];
    ts[t] = s;
    __syncthreads();
    for (int off = 1; off < 256; off <<= 1) {
        int v = (t >= off) ? ts[t - off] : 0;
        __syncthreads();
        ts[t] += v;
        __syncthreads();
    }
    int pre = partial[b] + ((t == 0) ? 0 : ts[t - 1]);
#pragma unroll
    for (int j = 0; j < 4; ++j) {
        int idx = base + j;
        if (idx < n) {
            row_ptr[idx] = pre;
            fill[idx] = pre;
            if (idx == n - 1) row_ptr[n] = pre + c[j];
            pre += c[j];
        }
    }
}

__global__ void scatter_kernel(const int* __restrict__ src, const int* __restrict__ dst,
                               const float* __restrict__ w, int* __restrict__ fill,
                               int2* __restrict__ epk, int E) {
    int i = blockIdx.x * blockDim.x + threadIdx.x;
    if (i < E) {
        int d = dst[i];
        int pos = atomicAdd(&fill[d], 1);
        int2 m; m.x = src[i]; m.y = __builtin_bit_cast(int, w[i]);
        epk[pos] = m;
    }
}

// ---------------------------------------------------------------------------
// Weight transpose + bf16 convert: Wt[n][k] = bf16(W[k][n])
// ---------------------------------------------------------------------------
__global__ void wtrans_kernel(const float* __restrict__ W, unsigned short* __restrict__ Wt,
                              int K, int N) {
    int idx = blockIdx.x * blockDim.x + threadIdx.x;
    if (idx >= N * K) return;
    int n = idx / K, k = idx - n * K;
    Wt[idx] = f2bf(W[(size_t)k * N + n]);
}

// ---------------------------------------------------------------------------
// GEMM layer 1, depth-3 pipeline: Hb[M][256] = relu(X[M][512] @ W1t^T + b1)
// Tile 128x256 (full N), 512 threads (8 waves 2x4), BK=32, NBUF=4.
// stage(s+3) + vmcnt(12): 3 stages in flight covers ~900cy HBM latency.
// Buffer hazard: writer buf (s+3)&3 == (s-1)&3 whose reads finished before
// the end-barrier of iter s-1 (already passed by all waves) -> safe.
// ---------------------------------------------------------------------------
__global__ __launch_bounds__(512) void gemm1_pipe(const float* __restrict__ X,
                                                  const unsigned short* __restrict__ W1t,
                                                  const float* __restrict__ b1,
                                                  unsigned short* __restrict__ Hb, int M) {
    __shared__ char smem[131072];          // 4x16KB A (f32) + 4x16KB B (bf16)
    char* const Ab0 = smem;
    char* const Bb0 = smem + 65536;

    const int tid = threadIdx.x;
    const int lane = tid & 63;
    const int wv = tid >> 6;               // 0..7
    const int wr = wv >> 2, wc = wv & 3;   // 2 x 4 wave grid
    const int brow = blockIdx.x * 128;

    const char* asrc[2];
    int adst[2];
#pragma unroll
    for (int c = 0; c < 2; ++c) {
        int ar = brow + wv * 16 + (lane & 15); if (ar > M - 1) ar = M - 1;
        int k = (lane >> 4) * 8 + c * 4;
        asrc[c] = (const char*)&X[(size_t)ar * NFEAT + k];
        adst[c] = (wv + c * 8) * 1024;
    }
    const char* bsrc[2];
    int bdst[2];
#pragma unroll
    for (int c = 0; c < 2; ++c) {
        int ci = wv + c * 8;
        int col = ci * 16 + (lane & 15);
        bsrc[c] = (const char*)&W1t[(size_t)col * NFEAT + (lane >> 4) * 8];
        bdst[c] = ci * 1024;
    }

    f32x4 acc[4][4];
#pragma unroll
    for (int m = 0; m < 4; ++m)
#pragma unroll
        for (int n = 0; n < 4; ++n) acc[m][n] = f32x4{0.f, 0.f, 0.f, 0.f};

    auto stage = [&](int buf, int step) {
#pragma unroll
        for (int c = 0; c < 2; ++c)
            gload_lds16(asrc[c] + (size_t)step * 128, Ab0 + buf * 16384 + adst[c]);
#pragma unroll
        for (int c = 0; c < 2; ++c)
            gload_lds16(bsrc[c] + (size_t)step * 64, Bb0 + buf * 16384 + bdst[c]);
    };

    constexpr int NSTEP = NFEAT / 32;      // 16
    stage(0, 0);
    stage(1, 1);
    stage(2, 2);

    for (int s = 0; s < NSTEP; ++s) {
        if (s + 3 < NSTEP) {
            stage((s + 3) & 3, s + 3);
            asm volatile("s_waitcnt vmcnt(12)" ::: "memory");
        } else if (s + 2 < NSTEP) {
            asm volatile("s_waitcnt vmcnt(8)" ::: "memory");
        } else if (s + 1 < NSTEP) {
            asm volatile("s_waitcnt vmcnt(4)" ::: "memory");
        } else {
            asm volatile("s_waitcnt vmcnt(0)" ::: "memory");
        }
        __builtin_amdgcn_s_barrier();
        asm volatile("" ::: "memory");

        const char* Abuf = Ab0 + (s & 3) * 16384;
        const char* Bbuf = Bb0 + (s & 3) * 16384;
        short8v a[4], b[4];
#pragma unroll
        for (int m = 0; m < 4; ++m) {
            int g = ((wr * 4 + m) * 64 + lane) * 16;
            f32x4 lo = *(const f32x4*)(Abuf + g);
            f32x4 hi = *(const f32x4*)(Abuf + 8192 + g);
            uint4 u;
            u.x = cvtpk2(lo[0], lo[1]); u.y = cvtpk2(lo[2], lo[3]);
            u.z = cvtpk2(hi[0], hi[1]); u.w = cvtpk2(hi[2], hi[3]);
            a[m] = __builtin_bit_cast(short8v, u);
        }
#pragma unroll
        for (int n = 0; n < 4; ++n)
            b[n] = *(const short8v*)(Bbuf + ((wc * 4 + n) * 64 + lane) * 16);
#pragma unroll
        for (int m = 0; m < 4; ++m)
#pragma unroll
            for (int n = 0; n < 4; ++n)
                acc[m][n] = __builtin_amdgcn_mfma_f32_16x16x32_bf16(a[m], b[n], acc[m][n], 0, 0, 0);

        __builtin_amdgcn_s_barrier();
        asm volatile("" ::: "memory");
    }

#pragma unroll
    for (int n = 0; n < 4; ++n) {
        int colg = wc * 64 + n * 16 + (lane & 15);
        float bv = b1[colg];
#pragma unroll
        for (int m = 0; m < 4; ++m) {
#pragma unroll
            for (int r = 0; r < 4; ++r) {
                int rowg = brow + wr * 64 + m * 16 + (lane >> 4) * 4 + r;
                if (rowg < M) {
                    float v = fmaxf(acc[m][n][r] + bv, 0.f);
                    Hb[(size_t)rowg * NHID + colg] = f2bf(v);
                }
            }
        }
    }
}

// ---------------------------------------------------------------------------
// GEMM layer 2, depth-3 pipeline: C0[M][128] = Hb[M][256] @ W2t^T + b2
// Tile 128x128, 256 threads (4 waves 2x2), BK=32, NBUF=4. LDS 64KB.
// ---------------------------------------------------------------------------
__global__ __launch_bounds__(256) void gemm2_pipe(const unsigned short* __restrict__ Hb,
                                                  const unsigned short* __restrict__ W2t,
                                                  const float* __restrict__ b2,
                                                  unsigned short* __restrict__ C0, int M) {
    __shared__ char smem[65536];           // 4x8KB A + 4x8KB B
    char* const Ab0 = smem;
    char* const Bb0 = smem + 32768;

    const int tid = threadIdx.x;
    const int lane = tid & 63;
    const int wv = tid >> 6;               // 0..3
    const int wr = wv >> 1, wc = wv & 1;
    const int brow = blockIdx.x * 128;

    const char* asrc[2];
    const char* bsrc[2];
    int adst[2], bdst[2];
#pragma unroll
    for (int c = 0; c < 2; ++c) {
        int ci = wv + c * 4;               // 0..7
        int ar = brow + ci * 16 + (lane & 15); if (ar > M - 1) ar = M - 1;
        asrc[c] = (const char*)&Hb[(size_t)ar * NHID + (lane >> 4) * 8];
        adst[c] = ci * 1024;
        int col = ci * 16 + (lane & 15);
        bsrc[c] = (const char*)&W2t[(size_t)col * NHID + (lane >> 4) * 8];
        bdst[c] = ci * 1024;
    }

    f32x4 acc[4][4];
#pragma unroll
    for (int m = 0; m < 4; ++m)
#pragma unroll
        for (int n = 0; n < 4; ++n) acc[m][n] = f32x4{0.f, 0.f, 0.f, 0.f};

    auto stage = [&](int buf, int step) {
#pragma unroll
        for (int c = 0; c < 2; ++c)
            gload_lds16(asrc[c] + (size_t)step * 64, Ab0 + buf * 8192 + adst[c]);
#pragma unroll
        for (int c = 0; c < 2; ++c)
            gload_lds16(bsrc[c] + (size_t)step * 64, Bb0 + buf * 8192 + bdst[c]);
    };

    constexpr int NSTEP = NHID / 32;       // 8
    stage(0, 0);
    stage(1, 1);
    stage(2, 2);

    for (int s = 0; s < NSTEP; ++s) {
        if (s + 3 < NSTEP) {
            stage((s + 3) & 3, s + 3);
            asm volatile("s_waitcnt vmcnt(12)" ::: "memory");
        } else if (s + 2 < NSTEP) {
            asm volatile("s_waitcnt vmcnt(8)" ::: "memory");
        } else if (s + 1 < NSTEP) {
            asm volatile("s_waitcnt vmcnt(4)" ::: "memory");
        } else {
            asm volatile("s_waitcnt vmcnt(0)" ::: "memory");
        }
        __builtin_amdgcn_s_barrier();
        asm volatile("" ::: "memory");

        const char* Abuf = Ab0 + (s & 3) * 8192;
        const char* Bbuf = Bb0 + (s & 3) * 8192;
        short8v a[4], b[4];
#pragma unroll
        for (int m = 0; m < 4; ++m)
            a[m] = *(const short8v*)(Abuf + ((wr * 4 + m) * 64 + lane) * 16);
#pragma unroll
        for (int n = 0; n < 4; ++n)
            b[n] = *(const short8v*)(Bbuf + ((wc * 4 + n) * 64 + lane) * 16);
#pragma unroll
        for (int m = 0; m < 4; ++m)
#pragma unroll
            for (int n = 0; n < 4; ++n)
                acc[m][n] = __builtin_amdgcn_mfma_f32_16x16x32_bf16(a[m], b[n], acc[m][n], 0, 0, 0);

        __builtin_amdgcn_s_barrier();
        asm volatile("" ::: "memory");
    }

#pragma unroll
    for (int n = 0; n < 4; ++n) {
        int colg = wc * 64 + n * 16 + (lane & 15);
        float bv = b2[colg];
#pragma unroll
        for (int m = 0; m < 4; ++m) {
#pragma unroll
            for (int r = 0; r < 4; ++r) {
                int rowg = brow + wr * 64 + m * 16 + (lane >> 4) * 4 + r;
                if (rowg < M)
                    C0[(size_t)rowg * NCLASS + colg] = f2bf(acc[m][n][r] + bv);
            }
        }
    }
}

// ---------------------------------------------------------------------------
// One propagation hop (pull over CSR-by-dst), bf16 carry, packed int2 edges.
// (R5 structure — known 88us/hop.) One wave per node; lanes preload up to 64
// edges' metadata (one 8B load), broadcast via readlane. Unroll 8 for MLP.
// FINAL=1: fuse log-softmax, write f32 to outf.
// ---------------------------------------------------------------------------
template<int FINAL>
__global__ __launch_bounds__(256) void hop_kernel(const unsigned short* __restrict__ carry,
                                                  const unsigned short* __restrict__ c0,
                                                  const int* __restrict__ rp,
                                                  const int2* __restrict__ epk,
                                                  unsigned short* __restrict__ outb,
                                                  float* __restrict__ outf, int nnodes) {
    int node = blockIdx.x * 4 + (threadIdx.x >> 6);
    if (node >= nnodes) return;
    int lane = threadIdx.x & 63;
    int e0 = rp[node], e1 = rp[node + 1];

    float a0x = 0.f, a0y = 0.f, a1x = 0.f, a1y = 0.f;
    float a2x = 0.f, a2y = 0.f, a3x = 0.f, a3y = 0.f;

    for (int eb = e0; eb < e1; eb += 64) {
        int nb = e1 - eb; if (nb > 64) nb = 64;
        int cs = 0, wvi = 0;
        if (lane < nb) {
            int2 m = epk[eb + lane];
            cs = m.x; wvi = m.y;
        }
        int j = 0;
        for (; j + 7 < nb; j += 8) {
            int s0 = __builtin_amdgcn_readlane(cs, j);
            int s1 = __builtin_amdgcn_readlane(cs, j + 1);
            int s2 = __builtin_amdgcn_readlane(cs, j + 2);
            int s3 = __builtin_amdgcn_readlane(cs, j + 3);
            int s4 = __builtin_amdgcn_readlane(cs, j + 4);
            int s5 = __builtin_amdgcn_readlane(cs, j + 5);
            int s6 = __builtin_amdgcn_readlane(cs, j + 6);
            int s7 = __builtin_amdgcn_readlane(cs, j + 7);
            float w0 = __builtin_bit_cast(float, __builtin_amdgcn_readlane(wvi, j));
            float w1 = __builtin_bit_cast(float, __builtin_amdgcn_readlane(wvi, j + 1));
            float w2 = __builtin_bit_cast(float, __builtin_amdgcn_readlane(wvi, j + 2));
            float w3 = __builtin_bit_cast(float, __builtin_amdgcn_readlane(wvi, j + 3));
            float w4 = __builtin_bit_cast(float, __builtin_amdgcn_readlane(wvi, j + 4));
            float w5 = __builtin_bit_cast(float, __builtin_amdgcn_readlane(wvi, j + 5));
            float w6 = __builtin_bit_cast(float, __builtin_amdgcn_readlane(wvi, j + 6));
            float w7 = __builtin_bit_cast(float, __builtin_amdgcn_readlane(wvi, j + 7));
            unsigned u0 = ((const unsigned*)(carry + ((size_t)s0 << 7)))[lane];
            unsigned u1 = ((const unsigned*)(carry + ((size_t)s1 << 7)))[lane];
            unsigned u2 = ((const unsigned*)(carry + ((size_t)s2 << 7)))[lane];
            unsigned u3 = ((const unsigned*)(carry + ((size_t)s3 << 7)))[lane];
            unsigned u4 = ((const unsigned*)(carry + ((size_t)s4 << 7)))[lane];
            unsigned u5 = ((const unsigned*)(carry + ((size_t)s5 << 7)))[lane];
            unsigned u6 = ((const unsigned*)(carry + ((size_t)s6 << 7)))[lane];
            unsigned u7 = ((const unsigned*)(carry + ((size_t)s7 << 7)))[lane];
            a0x = fmaf(w0, bflo(u0), a0x); a0y = fmaf(w0, bfhi(u0), a0y);
            a1x = fmaf(w1, bflo(u1), a1x); a1y = fmaf(w1, bfhi(u1), a1y);
            a2x = fmaf(w2, bflo(u2), a2x); a2y = fmaf(w2, bfhi(u2), a2y);
            a3x = fmaf(w3, bflo(u3), a3x); a3y = fmaf(w3, bfhi(u3), a3y);
            a0x = fmaf(w4, bflo(u4), a0x); a0y = fmaf(w4, bfhi(u4), a0y);
            a1x = fmaf(w5, bflo(u5), a1x); a1y = fmaf(w5, bfhi(u5), a1y);
            a2x = fmaf(w6, bflo(u6), a2x); a2y = fmaf(w6, bfhi(u6), a2y);
            a3x = fmaf(w7, bflo(u7), a3x); a3y = fmaf(w7, bfhi(u7), a3y);
        }
        for (; j + 3 < nb; j += 4) {
            int s0 = __builtin_amdgcn_readlane(cs, j);
            int s1 = __builtin_amdgcn_readlane(cs, j + 1);
            int s2 = __builtin_amdgcn_readlane(cs, j + 2);
            int s3 = __builtin_amdgcn_readlane(cs, j + 3);
            float w0 = __builtin_bit_cast(float, __builtin_amdgcn_readlane(wvi, j));
            float w1 = __builtin_bit_cast(float, __builtin_amdgcn_readlane(wvi, j + 1));
            float w2 = __builtin_bit_cast(float, __builtin_amdgcn_readlane(wvi, j + 2));
            float w3 = __builtin_bit_cast(float, __builtin_amdgcn_readlane(wvi, j + 3));
            unsigned u0 = ((const unsigned*)(carry + ((size_t)s0 << 7)))[lane];
            unsigned u1 = ((const unsigned*)(carry + ((size_t)s1 << 7)))[lane];
            unsigned u2 = ((const unsigned*)(carry + ((size_t)s2 << 7)))[lane];
            unsigned u3 = ((const unsigned*)(carry + ((size_t)s3 << 7)))[lane];
            a0x = fmaf(w0, bflo(u0), a0x); a0y = fmaf(w0, bfhi(u0), a0y);
            a1x = fmaf(w1, bflo(u1), a1x); a1y = fmaf(w1, bfhi(u1), a1y);
            a2x = fmaf(w2, bflo(u2), a2x); a2y = fmaf(w2, bfhi(u2), a2y);
            a3x = fmaf(w3, bflo(u3), a3x); a3y = fmaf(w3, bfhi(u3), a3y);
        }
        for (; j < nb; ++j) {
            int s0 = __builtin_amdgcn_readlane(cs, j);
            float w0 = __builtin_bit_cast(float, __builtin_amdgcn_readlane(wvi, j));
            unsigned u0 = ((const unsigned*)(carry + ((size_t)s0 << 7)))[lane];
            a0x = fmaf(w0, bflo(u0), a0x); a0y = fmaf(w0, bfhi(u0), a0y);
        }
    }

    unsigned ux = ((const unsigned*)(c0 + ((size_t)node << 7)))[lane];
    float vx = (1.f - ALPHA) * (a0x + a1x + a2x + a3x) + ALPHA * bflo(ux);
    float vy = (1.f - ALPHA) * (a0y + a1y + a2y + a3y) + ALPHA * bfhi(ux);

    if (FINAL) {
        float mx = fmaxf(vx, vy);
#pragma unroll
        for (int off = 32; off; off >>= 1) mx = fmaxf(mx, __shfl_xor(mx, off, 64));
        float se = __expf(vx - mx) + __expf(vy - mx);
#pragma unroll
        for (int off = 32; off; off >>= 1) se += __shfl_xor(se, off, 64);
        float l = mx + __logf(se);
        float2 o; o.x = vx - l; o.y = vy - l;
        ((float2*)(outf + ((size_t)node << 7)))[lane] = o;
    } else {
        unsigned o = (unsigned)f2bf(vx) | ((unsigned)f2bf(vy) << 16);
        ((unsigned*)(outb + ((size_t)node << 7)))[lane] = o;
    }
}

// ---------------------------------------------------------------------------

extern "C" void kernel_launch(void* const* d_in, const int* in_sizes, int n_in,
                              void* d_out, int out_size, void* d_ws, size_t ws_size,
                              hipStream_t stream) {
    const float* x   = (const float*)d_in[0];
    const int*   ei  = (const int*)d_in[1];
    const float* ew  = (const float*)d_in[2];
    const float* W1  = (const float*)d_in[3];
    const float* b1  = (const float*)d_in[4];
    const float* W2  = (const float*)d_in[5];
    const float* b2  = (const float*)d_in[6];
    float* outp = (float*)d_out;

    const int E = in_sizes[1] / 2;
    const int Nn = N_NODES;
    const int* srcv = ei;
    const int* dstv = ei + E;
    const size_t NC = (size_t)Nn * NCLASS;   // 12.8M elements

    // workspace layout (16B-aligned buffers)
    unsigned short* c0  = (unsigned short*)d_ws;    // bf16 x0 copy     [NC]
    unsigned short* A16 = c0 + NC;                  // ping             [NC]
    unsigned short* B16 = A16 + NC;                 // pong             [NC]
    unsigned short* hb  = A16;                      // H bf16 overlay (dead before hops)
    unsigned short* w1t = B16 + NC;                 // 256x512
    unsigned short* w2t = w1t + NHID * NFEAT;       // 128x256
    int* row_ptr = (int*)(w2t + NCLASS * NHID);     // Nn+1
    int* fill    = row_ptr + (Nn + 1);              // Nn (counts)
    int* partial = fill + Nn;                       // 128
    int2* epk    = (int2*)(partial + 128);          // E packed {src, w}

    const int NB = (Nn + 1023) / 1024;              // 98 scan blocks

    // ---- CSR build ----
    hipMemsetAsync(fill, 0, (size_t)Nn * sizeof(int), stream);
    count_kernel<<<(E + 255) / 256, 256, 0, stream>>>(dstv, fill, E);
    scan_p1<<<NB, 256, 0, stream>>>(fill, partial, Nn);
    scan_p2<<<1, 128, 0, stream>>>(partial, NB);
    scan_p3<<<NB, 256, 0, stream>>>(fill, partial, row_ptr, fill, Nn);
    scatter_kernel<<<(E + 255) / 256, 256, 0, stream>>>(srcv, dstv, ew, fill, epk, E);

    // ---- weight prep ----
    wtrans_kernel<<<(NHID * NFEAT + 255) / 256, 256, 0, stream>>>(W1, w1t, NFEAT, NHID);
    wtrans_kernel<<<(NCLASS * NHID + 255) / 256, 256, 0, stream>>>(W2, w2t, NHID, NCLASS);

    // ---- MLP (bf16 MFMA, depth-3 counted-vmcnt pipeline) ----
    {
        int gm = (Nn + 127) / 128;                  // 782
        gemm1_pipe<<<gm, 512, 0, stream>>>(x, w1t, b1, hb, Nn);
        gemm2_pipe<<<gm, 256, 0, stream>>>(hb, w2t, b2, c0, Nn);
    }

    // ---- K_HOPS propagation (bf16 carry), ping-pong; last hop fuses softmax ----
    int grid = (Nn + 3) / 4;
    const unsigned short* carry = c0;
    unsigned short* dsts[2] = {A16, B16};
    for (int k = 0; k < K_HOPS - 1; ++k) {
        unsigned short* o = dsts[k & 1];
        hop_kernel<0><<<grid, 256, 0, stream>>>(carry, c0, row_ptr, epk, o, nullptr, Nn);
        carry = o;
    }
    hop_kernel<1><<<grid, 256, 0, stream>>>(carry, c0, row_ptr, epk, nullptr, outp, Nn);
}